// Round 19
// baseline (14.594 us; speedup 1.0000x reference)
//
#include <hip/hip_runtime.h>

// Euler characteristic curve of sublevel cubical complex.
// x: [B,C,H,W] f32 -> out: [B,C,RES] f32.
//
// R15 single-kernel scaffold + LOWER-STAR inner loop: 1 ds_add per vertex
// (was 4). The 4-atomic kernel is LDS-atomic-pipe bound (128 wave-ops/thread
// x 16 waves/CU x ~10cyc ~= 8.5us of the 10.5us kernel); only fewer atomic
// instructions moves that floor. Prior lower-star attempts lost to
// confounds (2-block occupancy / 18-load register bloat under 102-cap /
// bpermute halos on the LDS pipe); this version: rolling 3-row window
// (24 live floats), scalar halo loads (idle VMEM pipe), byte-addr binq,
// launch_bounds(512,4) -> VGPR cap 128 (free: grid-limited 2 blocks/CU).
//
// Ownership (R3-hardware-verified exact): cell owner = largest-linear-index
// maximizing vertex; smaller-index neighbors compare <=, larger-index <.
//   w = 1 - #edges_owned + #faces_owned, ONE atomic at bin(x_v).
// Epilogue: rotated conflict-free reduce, 64-lane shfl scan, direct store.

#define HH 128
#define WW 128
#define RESB 64
#define NT 512
#define RPT 8            // rows per thread
#define BC 512           // one block per image

__global__ __launch_bounds__(NT, 4) void ecc_fused(const float* __restrict__ X,
                                                   float* __restrict__ out) {
    __shared__ int hist[RESB * 32];  // [bin][col], 8 KiB
    const int bc = blockIdx.x;
    const int tid = threadIdx.x;
    const int lnb = (tid & 31) << 2;  // lane-column byte offset, < 128
    const float* __restrict__ x = X + (size_t)bc * (HH * WW);

    ((int4*)hist)[tid] = make_int4(0, 0, 0, 0);  // 2048 dwords / 512 threads
    __syncthreads();

    char* const hb = (char*)hist;
    // binq as byte address: (ceil(F*63) << 7) + lnb.  F in [0,1) -> bin 0..63.
    auto binqa = [lnb](float F) {
        return ((int)ceilf(F * 63.0f) << 7) + lnb;
    };

    const int col4 = tid & 31;   // which float4 of the row
    const int rg = tid >> 5;     // 0..15 row group
    const int r0 = rg * RPT;
    const int c0 = col4 * 4;
    const int cL = (col4 > 0) ? c0 - 1 : 0;          // left halo col (k=0 masked)
    const int cR = (col4 < 31) ? c0 + 4 : WW - 1;    // right halo col (k=3 masked)

    // Rolling 3-row window {U,M,D} of 6 cols; P = prefetch.
    float U[6], M[6], D[6];
#define LOADROW(rr_, row_)                                                   \
    {                                                                        \
        const int rr = ((rr_) < 0) ? 0 : (((rr_) > HH - 1) ? HH - 1 : (rr_)); \
        const float* rp = x + rr * WW;                                       \
        const float4 a = *(const float4*)(rp + c0);                          \
        (row_)[1] = a.x; (row_)[2] = a.y; (row_)[3] = a.z; (row_)[4] = a.w;  \
        (row_)[0] = rp[cL];                                                  \
        (row_)[5] = rp[cR];                                                  \
    }
    LOADROW(r0 - 1, U)   // garbage-clamped when rg==0 (masked by hU)
    LOADROW(r0, M)
    LOADROW(r0 + 1, D)

    const int hl0 = (col4 > 0) ? 1 : 0;   // k==0 left neighbor exists
    const int hr3 = (col4 < 31) ? 1 : 0;  // k==3 right neighbor exists
    const int hU0 = (r0 > 0) ? 1 : 0;     // dr==0 up row exists (rg>0)
    const int hD7 = (rg < 15) ? 1 : 0;    // dr==7 down row exists

#pragma unroll
    for (int dr = 0; dr < RPT; ++dr) {
        const int hU = (dr > 0) ? 1 : hU0;  // folds to 1 for dr>0
        const int hD = (dr < RPT - 1) ? 1 : hD7;
        // Prefetch next D row before compute (lands under the VALU work).
        float P[6];
        if (dr < RPT - 1) { LOADROW(r0 + dr + 2, P) }
#pragma unroll
        for (int k = 0; k < 4; ++k) {
            const int hl = (k > 0) ? 1 : hl0;   // folds for k>0
            const int hr = (k < 3) ? 1 : hr3;   // folds for k<3
            const float xv = M[k + 1];
            // ownership predicates (smaller-index: <=, larger-index: <)
            const int pL = hl & (M[k] <= xv ? 1 : 0);
            const int pR = hr & (M[k + 2] < xv ? 1 : 0);
            const int pU = hU & (U[k + 1] <= xv ? 1 : 0);
            const int pD = hD & (D[k + 1] < xv ? 1 : 0);
            const int w = 1 - pL - pR - pU - pD
                + (pU & pL & (U[k] <= xv ? 1 : 0))
                + (pU & pR & (U[k + 2] <= xv ? 1 : 0))
                + (pD & pL & (D[k] < xv ? 1 : 0))
                + (pD & pR & (D[k + 2] < xv ? 1 : 0));
            atomicAdd((int*)(hb + binqa(xv)), w);  // ONE ds_add / vertex
        }
        if (dr < RPT - 1) {
#pragma unroll
            for (int t = 0; t < 6; ++t) { U[t] = M[t]; M[t] = D[t]; D[t] = P[t]; }
        }
    }
#undef LOADROW
    __syncthreads();

    // Reduce over 32 columns: thread (bin = tid&63, q = tid>>6 in 0..7) sums 4,
    // rotated -> all 32 banks covered, 2 lanes/bank = free.
    const int bin = tid & 63;
    const int q = tid >> 6;
    int ssum = 0;
#pragma unroll
    for (int k = 0; k < 4; ++k) {
        ssum += hist[(bin << 5) + ((q * 4 + bin + k) & 31)];
    }
    __syncthreads();
    hist[tid] = ssum;  // partial at [q*64 + bin]
    __syncthreads();
    if (tid < RESB) {
        int vv = 0;
#pragma unroll
        for (int qq = 0; qq < 8; ++qq) vv += hist[qq * 64 + tid];
        // Inclusive prefix scan across 64 lanes (= bins) -> cumsum.
#pragma unroll
        for (int d = 1; d < 64; d <<= 1) {
            const int up = __shfl_up(vv, d, 64);
            if (tid >= d) vv += up;
        }
        out[bc * RESB + tid] = (float)vv;
    }
}

extern "C" void kernel_launch(void* const* d_in, const int* in_sizes, int n_in,
                              void* d_out, int out_size, void* d_ws, size_t ws_size,
                              hipStream_t stream) {
    const float* x = (const float*)d_in[0];
    float* out = (float*)d_out;
    ecc_fused<<<BC, NT, 0, stream>>>(x, out);
}

// Round 20
// 11.378 us; speedup vs baseline: 1.2827x; 1.2827x over previous
//
#include <hip/hip_runtime.h>

// Euler characteristic curve of sublevel cubical complex.
// x: [B,C,H,W] f32 -> out: [B,C,RES] f32.
//
// R17 inner loop (proven 11.54us), single structural change: NT 512 -> 1024.
//   Grid 512 (one block/image) was occupancy-limited to 16 waves/CU; pipes
//   are balanced (R18: lower-star's 4x atomic cut LOSES; R17: VALU shave
//   ~neutral), so the remaining slack is issue interleave -> double waves.
//   NT=1024: 16 waves/block, 2 blocks/CU = 32 waves/CU (100%).
//   launch_bounds(1024,8) -> VGPR cap 64; rolling window state ~40 VGPR
//   (lean, unlike R6's cap-64 spill with 21 simultaneously-live values).
//   - 4 rows/thread (32 row groups), depth-1 prefetch; byte-addr binq;
//     branchless 4 ds_add per vertex; hist[bin][col] int32 x 32 (8 KiB);
//     rotated conflict-free reduce; 64-lane shfl scan; direct store.

#define HH 128
#define WW 128
#define RESB 64
#define NT 1024
#define RPT 4            // rows per thread
#define BC 512           // one block per image

__global__ __launch_bounds__(NT, 8) void ecc_fused(const float* __restrict__ X,
                                                   float* __restrict__ out) {
    __shared__ int hist[RESB * 32];  // [bin][col], 8 KiB
    const int bc = blockIdx.x;
    const int tid = threadIdx.x;
    const int lnb = (tid & 31) << 2;  // lane-column byte offset, < 128
    const float* __restrict__ x = X + (size_t)bc * (HH * WW);

    ((int2*)hist)[tid] = make_int2(0, 0);  // 2048 dwords / 1024 threads
    __syncthreads();

    char* const hb = (char*)hist;
    // binq as byte address: (ceil(F*63) << 7) + lnb.  F in [0,1) -> bin 0..63.
    auto binqa = [lnb](float F) {
        return ((int)ceilf(F * 63.0f) << 7) + lnb;
    };

    const int col4 = tid & 31;   // which float4 of the row
    const int rg = tid >> 5;     // 0..31 row group
    const int r0 = rg * RPT;
    const int c0 = col4 * 4;
    const int cR = (col4 < 31) ? c0 + 4 : WW - 1;  // right halo col (k=3 masked)

    int u[5], v[5], w[5];
    {
        const float4 a = *(const float4*)(x + r0 * WW + c0);
        const float aR = x[r0 * WW + cR];
        u[0] = binqa(a.x); u[1] = binqa(a.y); u[2] = binqa(a.z); u[3] = binqa(a.w); u[4] = binqa(aR);
        const float4 b = *(const float4*)(x + (r0 + 1) * WW + c0);
        const float bR = x[(r0 + 1) * WW + cR];
        v[0] = binqa(b.x); v[1] = binqa(b.y); v[2] = binqa(b.z); v[3] = binqa(b.w); v[4] = binqa(bR);
    }

#pragma unroll
    for (int dr = 0; dr < RPT; ++dr) {
        // hD folds to 1 for dr<3; last thread-row (rg=31, row 127) masked.
        const int hD = (dr < RPT - 1) ? 1 : ((rg < 31) ? 1 : 0);
        // Prefetch row r0+dr+2 (clamped) BEFORE compute -> load lands under it.
        float4 p4; float pR;
        if (dr < RPT - 1) {
            const int rn = (r0 + dr + 2 < HH) ? r0 + dr + 2 : HH - 1;
            p4 = *(const float4*)(x + rn * WW + c0);
            pR = x[rn * WW + cR];
        }
#pragma unroll
        for (int k = 0; k < 4; ++k) {
            const int hR = (k < 3) ? 1 : ((col4 < 31) ? 1 : 0);  // folds for k<3
            const int u00 = u[k];
            const int bh  = max(u00, u[k + 1]);
            const int bvv = max(u00, v[k]);
            const int bf  = max(bh, max(v[k], v[k + 1]));
            atomicAdd((int*)(hb + u00), 1);          // vertex +
            atomicAdd((int*)(hb + bh),  -hR);        // h-edge -
            atomicAdd((int*)(hb + bvv), -hD);        // v-edge -
            atomicAdd((int*)(hb + bf),  hR & hD);    // face  +
        }
        if (dr < RPT - 1) {
            w[0] = binqa(p4.x); w[1] = binqa(p4.y); w[2] = binqa(p4.z); w[3] = binqa(p4.w); w[4] = binqa(pR);
#pragma unroll
            for (int k = 0; k < 5; ++k) { u[k] = v[k]; v[k] = w[k]; }
        }
    }
    __syncthreads();

    // Reduce over 32 columns: thread (bin = tid&63, q = tid>>6 in 0..15) sums 2,
    // rotated -> banks spread, 2 lanes/bank = free.
    const int bin = tid & 63;
    const int q = tid >> 6;
    int ssum = 0;
#pragma unroll
    for (int k = 0; k < 2; ++k) {
        ssum += hist[(bin << 5) + ((q * 2 + bin + k) & 31)];
    }
    __syncthreads();
    hist[tid] = ssum;  // partial at [q*64 + bin], 1024 slots of 2048
    __syncthreads();
    if (tid < RESB) {
        int vv = 0;
#pragma unroll
        for (int qq = 0; qq < 16; ++qq) vv += hist[qq * 64 + tid];
        // Inclusive prefix scan across 64 lanes (= bins) -> cumsum.
#pragma unroll
        for (int d = 1; d < 64; d <<= 1) {
            const int up = __shfl_up(vv, d, 64);
            if (tid >= d) vv += up;
        }
        out[bc * RESB + tid] = (float)vv;
    }
}

extern "C" void kernel_launch(void* const* d_in, const int* in_sizes, int n_in,
                              void* d_out, int out_size, void* d_ws, size_t ws_size,
                              hipStream_t stream) {
    const float* x = (const float*)d_in[0];
    float* out = (float*)d_out;
    ecc_fused<<<BC, NT, 0, stream>>>(x, out);
}